// Round 5
// baseline (59.545 us; speedup 1.0000x reference)
//
#include <hip/hip_runtime.h>
#include <math.h>

// Problem constants
#define BB 512
#define TT 8000
#define CH 4             // chunks per batch
#define TC 2000          // elements per chunk
#define NACC 13          // 3 SP + 9 XT + 1 msum
#define NW 16            // waves per block (1024 threads)
#define NF4 3500         // flat f4 stream: 1500 pred + 1500 tgt + 500 mask
#define NINST 55         // ceil(3500/64) wave-instructions to stage a chunk

__device__ __forceinline__ void accum_elem(float acc[NACC], float m,
                                           float x0, float x1, float x2,
                                           float t0, float t1, float t2) {
    acc[12] += m;
    float x[3] = {x0, x1, x2};
    float t[3] = {t0, t1, t2};
    #pragma unroll
    for (int i = 0; i < 3; i++) {
        float xi = x[i];
        float sp = fmaxf(xi, 0.0f) + __logf(1.0f + __expf(-fabsf(xi)));
        acc[i] = fmaf(m, sp, acc[i]);
        float mx = m * xi;
        #pragma unroll
        for (int j = 0; j < 3; j++)
            acc[3 + i*3 + j] = fmaf(mx, t[j], acc[3 + i*3 + j]);
    }
}

// One block per (b, chunk): stage the whole 56 KB chunk to LDS with DENSE
// global_load_lds (flat f4 stream, per-lane source select), one barrier,
// element-aligned compute, one block reduction.
__global__ __launch_bounds__(1024, 8) void pit_stage(
        const float* __restrict__ pred,
        const float* __restrict__ tgt,
        const float* __restrict__ mask,
        double* __restrict__ partials) {
    __shared__ float lds[NF4 * 4 + 80];   // 14080 floats + clamp slack
    __shared__ float red[NW][NACC];

    int blk = blockIdx.x;
    int b = blk >> 2, c = blk & 3;
    int tid = threadIdx.x, lane = tid & 63, w = tid >> 6;
    const float* pb = pred + (size_t)b * (TT*3) + c * (TC*3);
    const float* tb = tgt  + (size_t)b * (TT*3) + c * (TC*3);
    const float* mb = mask + (size_t)b * TT + c * TC;

    // ---- Stage: 55 dense wave-instructions, round-robin over 16 waves ----
    #pragma unroll
    for (int k = 0; k < 4; k++) {
        int n = w + NW * k;               // wave-uniform instruction id
        if (n < NINST) {
            int q = n * 64 + lane;        // flat f4 index in [pred|tgt|mask]
            const float* src;
            if (q < 1500)       src = pb + 4 * q;
            else if (q < 3000)  src = tb + 4 * (q - 1500);
            else { int mq = q - 3000; mq = mq > 499 ? 499 : mq;
                   src = mb + 4 * mq; }
            __builtin_amdgcn_global_load_lds(
                (const __attribute__((address_space(1))) void*)src,
                (__attribute__((address_space(3))) void*)(lds + n * 256),
                16, 0, 0);
        }
    }
    asm volatile("s_waitcnt vmcnt(0)" ::: "memory");
    __syncthreads();

    // ---- Compute: threads 0..999 each handle an element pair ----
    float acc[NACC];
    #pragma unroll
    for (int k = 0; k < NACC; k++) acc[k] = 0.0f;

    if (tid < 1000) {
        int e = 2 * tid;
        const float* xp = lds + 3 * e;            // 6 floats (8B-aligned)
        const float* tp = lds + 6000 + 3 * e;
        float m0 = lds[12000 + e], m1 = lds[12000 + e + 1];
        accum_elem(acc, m0, xp[0], xp[1], xp[2], tp[0], tp[1], tp[2]);
        accum_elem(acc, m1, xp[3], xp[4], xp[5], tp[3], tp[4], tp[5]);
    }

    // ---- Wave butterfly (f32), cross-wave via LDS, thread 0 writes double ----
    #pragma unroll
    for (int k = 0; k < NACC; k++) {
        float v = acc[k];
        #pragma unroll
        for (int o = 32; o > 0; o >>= 1) v += __shfl_xor(v, o, 64);
        acc[k] = v;
    }
    if (lane == 0) {
        #pragma unroll
        for (int k = 0; k < NACC; k++) red[w][k] = acc[k];
    }
    __syncthreads();
    if (tid == 0) {
        #pragma unroll
        for (int k = 0; k < NACC; k++) {
            double s = 0.0;
            #pragma unroll
            for (int i = 0; i < NW; i++) s += (double)red[i][k];
            partials[(size_t)blk * NACC + k] = s;
        }
    }
}

// Epilogue: one block, 512 threads (thread == batch b).
// Sum 4 chunk-partials, build cost, argmin over 6 perms, mean over B.
__global__ __launch_bounds__(512) void pit_final(
        const double* __restrict__ partials, float* __restrict__ out) {
    __shared__ double sd[8];
    int b = threadIdx.x;
    double a[NACC];
    #pragma unroll
    for (int k = 0; k < NACC; k++) {
        double s = 0.0;
        #pragma unroll
        for (int c = 0; c < CH; c++)
            s += partials[((size_t)(b * CH + c)) * NACC + k];
        a[k] = s;
    }
    double msum = a[12] + 1e-14;
    double cost[3][3];
    #pragma unroll
    for (int i = 0; i < 3; i++)
        #pragma unroll
        for (int j = 0; j < 3; j++)
            cost[i][j] = (a[i] - a[3 + i*3 + j]) / msum;

    const int perms[6][3] = {{0,1,2},{0,2,1},{1,0,2},{1,2,0},{2,0,1},{2,1,0}};
    double best = 1e300; int bidx = 0;
    #pragma unroll
    for (int p = 0; p < 6; p++) {
        double v = (cost[0][perms[p][0]] + cost[1][perms[p][1]] +
                    cost[2][perms[p][2]]) / 3.0;
        if (v < best) { best = v; bidx = p; }
    }
    out[1 + b] = (float)bidx;

    // Mean of best over 512 batches.
    double v = best;
    #pragma unroll
    for (int o = 32; o > 0; o >>= 1) v += __shfl_down(v, o, 64);
    int lane = b & 63, w = b >> 6;
    if (lane == 0) sd[w] = v;
    __syncthreads();
    if (b == 0) {
        double s = 0.0;
        #pragma unroll
        for (int i = 0; i < 8; i++) s += sd[i];
        out[0] = (float)(s / (double)BB);
    }
}

extern "C" void kernel_launch(void* const* d_in, const int* in_sizes, int n_in,
                              void* d_out, int out_size, void* d_ws, size_t ws_size,
                              hipStream_t stream) {
    const float* pred = (const float*)d_in[0];
    const float* tgt  = (const float*)d_in[1];
    const float* mask = (const float*)d_in[2];
    float* out = (float*)d_out;
    double* partials = (double*)d_ws;   // BB*CH*NACC doubles = 208 KB

    pit_stage<<<BB * CH, 1024, 0, stream>>>(pred, tgt, mask, partials);
    pit_final<<<1, 512, 0, stream>>>(partials, out);
}

// Round 6
// 31.921 us; speedup vs baseline: 1.8654x; 1.8654x over previous
//
#include <hip/hip_runtime.h>
#include <math.h>

// Problem constants (from reference setup_inputs)
#define BB 512
#define TT 8000
#define SS 3
#define CH 4            // T-chunks per batch
#define TC (TT/CH)      // 2000 t per chunk
#define NV (TC/4)       // 500 vec4 items (4 t each) per chunk
#define NACC 13         // 3 SP + 9 XT + 1 msum (padded to 16 in records)

__device__ __forceinline__ void accum_elem(float acc[NACC], float m,
                                           float x0, float x1, float x2,
                                           float t0, float t1, float t2) {
    acc[12] += m;
    float x[3] = {x0, x1, x2};
    float t[3] = {t0, t1, t2};
    #pragma unroll
    for (int i = 0; i < 3; i++) {
        float xi = x[i];
        float sp = fmaxf(xi, 0.0f) + __logf(1.0f + __expf(-fabsf(xi)));
        acc[i] = fmaf(m, sp, acc[i]);
        float mx = m * xi;
        #pragma unroll
        for (int j = 0; j < 3; j++)
            acc[3 + i*3 + j] = fmaf(mx, t[j], acc[3 + i*3 + j]);
    }
}

__device__ __forceinline__ void accum_item(float acc[NACC],
                                           float4 pa, float4 pb, float4 pc,
                                           float4 ta, float4 tb, float4 tc,
                                           float4 mm) {
    accum_elem(acc, mm.x, pa.x, pa.y, pa.z, ta.x, ta.y, ta.z);
    accum_elem(acc, mm.y, pa.w, pb.x, pb.y, ta.w, tb.x, tb.y);
    accum_elem(acc, mm.z, pb.z, pb.w, pc.x, tb.z, tb.w, tc.x);
    accum_elem(acc, mm.w, pc.y, pc.z, pc.w, tc.y, tc.z, tc.w);
}

// Kernel 1: per (b, chunk) block-level partial sums of the 13 reductions.
// Exactly 2 items per thread, all 14 float4 loads issued before compute
// (register staging; LDS staging proven structurally worse in R4/R5).
// Tail: f32 wave butterfly -> LDS -> 16 threads write one 64 B record/block.
__global__ __launch_bounds__(256) void pit_partial(
        const float* __restrict__ pred,
        const float* __restrict__ tgt,
        const float* __restrict__ mask,
        float* __restrict__ bpart) {
    __shared__ float red[4][16];

    int blk = blockIdx.x;
    int b = blk >> 2, c = blk & 3;
    int tbase = c * TC;
    const float* pp = pred + ((size_t)b * TT + tbase) * 3;
    const float* tp = tgt  + ((size_t)b * TT + tbase) * 3;
    const float* mp = mask + (size_t)b * TT + tbase;

    int tid = threadIdx.x;
    int i0 = tid;                       // always < NV
    int i1 = tid + 256;
    bool v1 = (i1 < NV);
    int i1c = v1 ? i1 : (NV - 1);       // clamp: finite data, masked out

    // Issue all 14 independent float4 loads up front.
    const float4* p40 = (const float4*)(pp + (size_t)i0 * 12);
    const float4* t40 = (const float4*)(tp + (size_t)i0 * 12);
    float4 pa0 = p40[0], pb0 = p40[1], pc0 = p40[2];
    float4 ta0 = t40[0], tb0 = t40[1], tc0 = t40[2];
    float4 mm0 = *(const float4*)(mp + (size_t)i0 * 4);

    const float4* p41 = (const float4*)(pp + (size_t)i1c * 12);
    const float4* t41 = (const float4*)(tp + (size_t)i1c * 12);
    float4 pa1 = p41[0], pb1 = p41[1], pc1 = p41[2];
    float4 ta1 = t41[0], tb1 = t41[1], tc1 = t41[2];
    float4 mm1 = *(const float4*)(mp + (size_t)i1c * 4);
    if (!v1) { mm1.x = mm1.y = mm1.z = mm1.w = 0.0f; }

    float acc[NACC];
    #pragma unroll
    for (int k = 0; k < NACC; k++) acc[k] = 0.0f;

    accum_item(acc, pa0, pb0, pc0, ta0, tb0, tc0, mm0);
    accum_item(acc, pa1, pb1, pc1, ta1, tb1, tc1, mm1);

    // f32 butterfly reduce across the wave.
    #pragma unroll
    for (int k = 0; k < NACC; k++) {
        float v = acc[k];
        #pragma unroll
        for (int o = 32; o > 0; o >>= 1) v += __shfl_xor(v, o, 64);
        acc[k] = v;
    }

    int lane = tid & 63, w = tid >> 6;
    if (lane == 0) {
        #pragma unroll
        for (int k = 0; k < NACC; k++) red[w][k] = acc[k];
        red[w][13] = 0.0f; red[w][14] = 0.0f; red[w][15] = 0.0f;
    }
    __syncthreads();
    if (tid < 16) {
        float s = red[0][tid] + red[1][tid] + red[2][tid] + red[3][tid];
        bpart[(size_t)blk * 16 + tid] = s;   // coalesced 64 B record
    }
}

// Kernel 2 (fused epilogue, single block of 512): thread b sums its 4 chunk
// records (double), builds cost, argmin over 6 perms -> out[1+b]; then
// butterfly-mean over the 512 best values -> out[0]. Reads 128 KB total.
__global__ __launch_bounds__(512) void pit_final(
        const float* __restrict__ bpart, float* __restrict__ out) {
    __shared__ double sd[8];
    int b = threadIdx.x;

    double a[NACC];
    #pragma unroll
    for (int k = 0; k < NACC; k++) a[k] = 0.0;
    const float* r = bpart + (size_t)b * 64;   // 4 records x 16 floats
    #pragma unroll
    for (int c = 0; c < CH; c++)
        #pragma unroll
        for (int k = 0; k < NACC; k++)
            a[k] += (double)r[c * 16 + k];

    double msum = a[12] + 1e-14;
    double cost[3][3];
    #pragma unroll
    for (int i = 0; i < 3; i++)
        #pragma unroll
        for (int j = 0; j < 3; j++)
            cost[i][j] = (a[i] - a[3 + i*3 + j]) / msum;

    const int perms[6][3] = {{0,1,2},{0,2,1},{1,0,2},{1,2,0},{2,0,1},{2,1,0}};
    double best = 1e300; int bidx = 0;
    #pragma unroll
    for (int p = 0; p < 6; p++) {
        double v = (cost[0][perms[p][0]] + cost[1][perms[p][1]] +
                    cost[2][perms[p][2]]) / 3.0;
        if (v < best) { best = v; bidx = p; }
    }
    out[1 + b] = (float)bidx;

    // Mean of best over 512 batches (8 waves).
    double v = best;
    #pragma unroll
    for (int o = 32; o > 0; o >>= 1) v += __shfl_down(v, o, 64);
    int lane = b & 63, w = b >> 6;
    if (lane == 0) sd[w] = v;
    __syncthreads();
    if (b == 0) {
        double s = 0.0;
        #pragma unroll
        for (int i = 0; i < 8; i++) s += sd[i];
        out[0] = (float)(s / (double)BB);
    }
}

extern "C" void kernel_launch(void* const* d_in, const int* in_sizes, int n_in,
                              void* d_out, int out_size, void* d_ws, size_t ws_size,
                              hipStream_t stream) {
    const float* pred = (const float*)d_in[0];
    const float* tgt  = (const float*)d_in[1];
    const float* mask = (const float*)d_in[2];
    float* out = (float*)d_out;
    float* bpart = (float*)d_ws;   // BB*CH*16 floats = 128 KB

    pit_partial<<<BB * CH, 256, 0, stream>>>(pred, tgt, mask, bpart);
    pit_final<<<1, 512, 0, stream>>>(bpart, out);
}

// Round 7
// 30.297 us; speedup vs baseline: 1.9653x; 1.0536x over previous
//
#include <hip/hip_runtime.h>
#include <math.h>

// Problem constants (from reference setup_inputs)
#define BB 512
#define TT 8000
#define CH 4            // T-chunks per batch
#define TC (TT/CH)      // 2000 t per chunk
#define NACC 13         // 3 SP + 9 XT + 1 msum (padded to 16 in records)

__device__ __forceinline__ void accum_elem(float acc[NACC], float m,
                                           float x0, float x1, float x2,
                                           float t0, float t1, float t2) {
    acc[12] += m;
    float x[3] = {x0, x1, x2};
    float t[3] = {t0, t1, t2};
    #pragma unroll
    for (int i = 0; i < 3; i++) {
        float xi = x[i];
        float sp = fmaxf(xi, 0.0f) + __logf(1.0f + __expf(-fabsf(xi)));
        acc[i] = fmaf(m, sp, acc[i]);
        float mx = m * xi;
        #pragma unroll
        for (int j = 0; j < 3; j++)
            acc[3 + i*3 + j] = fmaf(mx, t[j], acc[3 + i*3 + j]);
    }
}

// Kernel 1: per (b, chunk) block partial sums. ONE t per thread per iteration:
// pred/tgt loads are dwordx3 at 12 B lane stride -> each wave-load covers a
// dense 768 B / 12-line window (minimal footprint, vs 48 lines for the old
// 48 B-stride float4 scheme). 8 independent unrolled iterations.
__global__ __launch_bounds__(256) void pit_partial(
        const float* __restrict__ pred,
        const float* __restrict__ tgt,
        const float* __restrict__ mask,
        float* __restrict__ bpart) {
    __shared__ float red[4][16];

    int blk = blockIdx.x;
    int b = blk >> 2, c = blk & 3;
    const float* pp = pred + ((size_t)b * TT + c * TC) * 3;
    const float* tp = tgt  + ((size_t)b * TT + c * TC) * 3;
    const float* mp = mask + (size_t)b * TT + c * TC;

    int tid = threadIdx.x;
    float acc[NACC];
    #pragma unroll
    for (int k = 0; k < NACC; k++) acc[k] = 0.0f;

    #pragma unroll
    for (int it = 0; it < 8; it++) {
        int t = tid + it * 256;             // 0..2047
        int tc_ = t < TC ? t : TC - 1;      // clamp: stays in-bounds
        float3 x3 = *(const float3*)(pp + 3 * (size_t)tc_);
        float3 g3 = *(const float3*)(tp + 3 * (size_t)tc_);
        float m = mp[tc_];
        m = (t < TC) ? m : 0.0f;            // zero contribution for clamped
        accum_elem(acc, m, x3.x, x3.y, x3.z, g3.x, g3.y, g3.z);
    }

    // f32 butterfly reduce across the wave.
    #pragma unroll
    for (int k = 0; k < NACC; k++) {
        float v = acc[k];
        #pragma unroll
        for (int o = 32; o > 0; o >>= 1) v += __shfl_xor(v, o, 64);
        acc[k] = v;
    }

    int lane = tid & 63, w = tid >> 6;
    if (lane == 0) {
        #pragma unroll
        for (int k = 0; k < NACC; k++) red[w][k] = acc[k];
        red[w][13] = 0.0f; red[w][14] = 0.0f; red[w][15] = 0.0f;
    }
    __syncthreads();
    if (tid < 16) {
        float s = red[0][tid] + red[1][tid] + red[2][tid] + red[3][tid];
        bpart[(size_t)blk * 16 + tid] = s;   // coalesced 64 B record
    }
}

// Kernel 2 (fused epilogue, single block of 512): thread b sums its 4 chunk
// records (double), builds cost, argmin over 6 perms -> out[1+b]; then
// butterfly-mean over the 512 best values -> out[0].
__global__ __launch_bounds__(512) void pit_final(
        const float* __restrict__ bpart, float* __restrict__ out) {
    __shared__ double sd[8];
    int b = threadIdx.x;

    double a[NACC];
    #pragma unroll
    for (int k = 0; k < NACC; k++) a[k] = 0.0;
    const float* r = bpart + (size_t)b * 64;   // 4 records x 16 floats
    #pragma unroll
    for (int c = 0; c < CH; c++)
        #pragma unroll
        for (int k = 0; k < NACC; k++)
            a[k] += (double)r[c * 16 + k];

    double msum = a[12] + 1e-14;
    double cost[3][3];
    #pragma unroll
    for (int i = 0; i < 3; i++)
        #pragma unroll
        for (int j = 0; j < 3; j++)
            cost[i][j] = (a[i] - a[3 + i*3 + j]) / msum;

    const int perms[6][3] = {{0,1,2},{0,2,1},{1,0,2},{1,2,0},{2,0,1},{2,1,0}};
    double best = 1e300; int bidx = 0;
    #pragma unroll
    for (int p = 0; p < 6; p++) {
        double v = (cost[0][perms[p][0]] + cost[1][perms[p][1]] +
                    cost[2][perms[p][2]]) / 3.0;
        if (v < best) { best = v; bidx = p; }
    }
    out[1 + b] = (float)bidx;

    // Mean of best over 512 batches (8 waves).
    double v = best;
    #pragma unroll
    for (int o = 32; o > 0; o >>= 1) v += __shfl_down(v, o, 64);
    int lane = b & 63, w = b >> 6;
    if (lane == 0) sd[w] = v;
    __syncthreads();
    if (b == 0) {
        double s = 0.0;
        #pragma unroll
        for (int i = 0; i < 8; i++) s += sd[i];
        out[0] = (float)(s / (double)BB);
    }
}

extern "C" void kernel_launch(void* const* d_in, const int* in_sizes, int n_in,
                              void* d_out, int out_size, void* d_ws, size_t ws_size,
                              hipStream_t stream) {
    const float* pred = (const float*)d_in[0];
    const float* tgt  = (const float*)d_in[1];
    const float* mask = (const float*)d_in[2];
    float* out = (float*)d_out;
    float* bpart = (float*)d_ws;   // BB*CH*16 floats = 128 KB

    pit_partial<<<BB * CH, 256, 0, stream>>>(pred, tgt, mask, bpart);
    pit_final<<<1, 512, 0, stream>>>(bpart, out);
}